// Round 6
// baseline (1982.910 us; speedup 1.0000x reference)
//
#include <hip/hip_runtime.h>
#include <math.h>

// Problem constants (B, T, D_IN, D_OUT) = (64, 1024, 512, 512)
#define BATCH   64
#define TSTEPS  1024
#define DIN     512
#define DH      512
#define MDIM    (BATCH * TSTEPS)
#define MB      16

// Fallback (round-5) K2 LDS layout: [8 waves][15 chunks][1024 B] B + 2 x 16 KiB H
#define BLDS_W   15360
#define BLDS_ALL 122880
#define K2_LDS   (BLDS_ALL + 2 * 16384)   // 155648 <= 163840

typedef _Float16 f16x8 __attribute__((ext_vector_type(8)));
typedef float    f32x4 __attribute__((ext_vector_type(4)));

__device__ inline unsigned short f2h_bits(float x) {
    _Float16 h = (_Float16)x;
    return __builtin_bit_cast(unsigned short, h);
}
// fast tanh: 1 - 2/(exp2(2x*log2e)+1); saturates correctly incl. inf
__device__ inline float ftanh(float x) {
    float e = __builtin_amdgcn_exp2f(x * 2.88539008177792681472f);
    return 1.0f - 2.0f * __builtin_amdgcn_rcpf(e + 1.0f);
}

// ---------------------------------------------------------------------------
// K1a: convert x (fp32) -> Xh (fp16)
// ---------------------------------------------------------------------------
__global__ __launch_bounds__(256) void convert_x(const float* __restrict__ x,
                                                 _Float16* __restrict__ xh,
                                                 int nvec) {
    int i = blockIdx.x * blockDim.x + threadIdx.x;
    int stride = gridDim.x * blockDim.x;
    for (; i < nvec; i += stride) {
        const float4* p = (const float4*)x + 2 * (size_t)i;
        float4 a = p[0], b = p[1];
        f16x8 o = { (_Float16)a.x, (_Float16)a.y, (_Float16)a.z, (_Float16)a.w,
                    (_Float16)b.x, (_Float16)b.y, (_Float16)b.z, (_Float16)b.w };
        ((f16x8*)xh)[i] = o;
    }
}

// ---------------------------------------------------------------------------
// K1b: Wt[n][k] = (fp16) W[k][n]   (also reused for Wr)
// ---------------------------------------------------------------------------
__global__ __launch_bounds__(256) void transpose_w(const float* __restrict__ W,
                                                   _Float16* __restrict__ Wt) {
    __shared__ float tile[64][65];
    const int t  = threadIdx.x;
    const int c  = t & 63;
    const int r0 = t >> 6;
    const int bn = blockIdx.x & 7;
    const int bk = blockIdx.x >> 3;
    const int k0 = bk * 64, n0 = bn * 64;
    #pragma unroll
    for (int i = 0; i < 16; ++i)
        tile[r0 + 4 * i][c] = W[(size_t)(k0 + r0 + 4 * i) * DH + n0 + c];
    __syncthreads();
    #pragma unroll
    for (int i = 0; i < 16; ++i)
        Wt[(size_t)(n0 + r0 + 4 * i) * DIN + k0 + c] = (_Float16)tile[c][r0 + 4 * i];
}

// ---------------------------------------------------------------------------
// K1d: pack slice-3 B-fragments (cols wv*64+48 .. +63) fragment-contiguous:
//   Wrp[wv*1024 + c*64 + lane] = frag (f16x8).
// ---------------------------------------------------------------------------
__global__ __launch_bounds__(512) void pack_b3(const _Float16* __restrict__ Wrt,
                                               _Float16* __restrict__ Wrp) {
    const int i  = blockIdx.x * 512 + threadIdx.x;   // 0..8191
    const int wv = i >> 10;
    const int c  = (i >> 6) & 15;
    const int l  = i & 63;
    const int col = wv * 64 + 48 + (l & 15);
    const int k0  = c * 32 + (l >> 4) * 8;
    ((f16x8*)Wrp)[i] = *(const f16x8*)&Wrt[(size_t)col * DIN + k0];
}

// ---------------------------------------------------------------------------
// K1c: XW = Xh @ Wt^T + bias via mfma_f32_16x16x32_f16 (validated earlier)
// ---------------------------------------------------------------------------
__global__ __launch_bounds__(256) void gemm_xw_mfma(const _Float16* __restrict__ Xh,
                                                    const _Float16* __restrict__ Wt,
                                                    const float* __restrict__ bias,
                                                    float* __restrict__ XW) {
    __shared__ __align__(16) _Float16 Ah[128][32];
    __shared__ __align__(16) _Float16 Bh[128][32];

    const int tid  = threadIdx.x;
    const int wv   = tid >> 6;
    const int lane = tid & 63;
    const int bn   = blockIdx.x & 3;
    const int bm   = blockIdx.x >> 2;
    const int m0   = bm * 128;
    const int n0   = bn * 128;

    const int mbase = (wv >> 1) * 64;
    const int nbase = (wv & 1) * 64;
    const int fr    = lane & 15;
    const int fq    = lane >> 4;

    f32x4 acc[4][4];
    #pragma unroll
    for (int i = 0; i < 4; ++i)
        #pragma unroll
        for (int j = 0; j < 4; ++j)
            acc[i][j] = (f32x4){0.f, 0.f, 0.f, 0.f};

    for (int kc = 0; kc < DIN / 32; ++kc) {
        const int k0 = kc * 32;
#if __has_builtin(__builtin_amdgcn_global_load_lds)
        #pragma unroll
        for (int q = 0; q < 2; ++q) {
            const int rb = wv * 2 + q;
            const int gr = (rb * 16) + (lane >> 2);
            const int gc = (lane & 3) * 8;
            const _Float16* ga = Xh + (size_t)(m0 + gr) * DIN + k0 + gc;
            const _Float16* gb = Wt + (size_t)(n0 + gr) * DIN + k0 + gc;
            __builtin_amdgcn_global_load_lds(
                (const __attribute__((address_space(1))) void*)ga,
                (__attribute__((address_space(3))) void*)&Ah[rb * 16][0], 16, 0, 0);
            __builtin_amdgcn_global_load_lds(
                (const __attribute__((address_space(1))) void*)gb,
                (__attribute__((address_space(3))) void*)&Bh[rb * 16][0], 16, 0, 0);
        }
#else
        #pragma unroll
        for (int q = 0; q < 2; ++q) {
            const int h0 = (q * 256 + tid) * 8;
            const int row = h0 >> 5, col = h0 & 31;
            *((uint4*)Ah + (q * 256 + tid)) =
                *(const uint4*)(Xh + (size_t)(m0 + row) * DIN + k0 + col);
            *((uint4*)Bh + (q * 256 + tid)) =
                *(const uint4*)(Wt + (size_t)(n0 + row) * DIN + k0 + col);
        }
#endif
        __syncthreads();

        f16x8 af[4], bf[4];
        #pragma unroll
        for (int mt = 0; mt < 4; ++mt)
            af[mt] = *(const f16x8*)&Ah[mbase + mt * 16 + fr][fq * 8];
        #pragma unroll
        for (int nt = 0; nt < 4; ++nt)
            bf[nt] = *(const f16x8*)&Bh[nbase + nt * 16 + fr][fq * 8];
        #pragma unroll
        for (int mt = 0; mt < 4; ++mt)
            #pragma unroll
            for (int nt = 0; nt < 4; ++nt)
                acc[mt][nt] = __builtin_amdgcn_mfma_f32_16x16x32_f16(
                    af[mt], bf[nt], acc[mt][nt], 0, 0, 0);
        __syncthreads();
    }

    #pragma unroll
    for (int nt = 0; nt < 4; ++nt) {
        const int col = n0 + nbase + nt * 16 + fr;
        const float bvl = bias[col];
        #pragma unroll
        for (int mt = 0; mt < 4; ++mt) {
            #pragma unroll
            for (int r = 0; r < 4; ++r) {
                const int row = m0 + mbase + mt * 16 + fq * 4 + r;
                XW[(size_t)row * DH + col] = acc[mt][nt][r] + bvl;
            }
        }
    }
}

// ---------------------------------------------------------------------------
// K1 fallback (fp32 VALU GEMM)
// ---------------------------------------------------------------------------
__global__ __launch_bounds__(256) void gemm_xw(const float* __restrict__ X,
                                               const float* __restrict__ W,
                                               const float* __restrict__ bias,
                                               float* __restrict__ XW) {
    __shared__ float As[16][68];
    __shared__ float Bs[16][68];
    const int tid = threadIdx.x;
    const int bx  = blockIdx.x & 7;
    const int by  = blockIdx.x >> 3;
    const int m0  = by * 64, n0 = bx * 64;
    const int ty = tid >> 4, tx = tid & 15;
    const int arow = tid >> 2, akq = (tid & 3) * 4;
    const int brow = tid >> 4, bcq = (tid & 15) * 4;
    float acc[4][4] = {{0.f}};
    for (int k0 = 0; k0 < DIN; k0 += 16) {
        float4 av = *(const float4*)&X[(size_t)(m0 + arow) * DIN + k0 + akq];
        float4 bv = *(const float4*)&W[(size_t)(k0 + brow) * DH + n0 + bcq];
        __syncthreads();
        As[akq + 0][arow] = av.x; As[akq + 1][arow] = av.y;
        As[akq + 2][arow] = av.z; As[akq + 3][arow] = av.w;
        *(float4*)&Bs[brow][bcq] = bv;
        __syncthreads();
        #pragma unroll
        for (int k = 0; k < 16; ++k) {
            float4 a = *(const float4*)&As[k][ty * 4];
            float4 b = *(const float4*)&Bs[k][tx * 4];
            float ar[4] = {a.x, a.y, a.z, a.w};
            float br[4] = {b.x, b.y, b.z, b.w};
            #pragma unroll
            for (int i = 0; i < 4; ++i)
                #pragma unroll
                for (int j = 0; j < 4; ++j)
                    acc[i][j] = fmaf(ar[i], br[j], acc[i][j]);
        }
    }
    float4 bv = *(const float4*)&bias[n0 + tx * 4];
    const float br[4] = {bv.x, bv.y, bv.z, bv.w};
    #pragma unroll
    for (int i = 0; i < 4; ++i) {
        float4 o;
        o.x = acc[i][0] + br[0]; o.y = acc[i][1] + br[1];
        o.z = acc[i][2] + br[2]; o.w = acc[i][3] + br[3];
        *(float4*)&XW[(size_t)(m0 + ty * 4 + i) * DH + n0 + tx * 4] = o;
    }
}

// ---------------------------------------------------------------------------
// K2a (preferred): FULL Wr residency. 4 wgs x 512 thr (8 waves).
//   slices 0..2 (48 frags) + slice-3 chunks 0..14 (15 frags) = 63 frags
//   = 252 regs (AGPR-file target, cap 256); slice-3 chunk 15 streamed from
//   L2 per step (round-5-proven hidden, laundered "+v").
//   => per-step LDS = 16 A-frag b128 reads/wave + epilogue writes ONLY
//      (round-5 paid 31 reads/wave). Static LDS 32 KiB.
// H fp16, fragment-linear (validated r2/r4/r5): conflict-free b128 A-reads.
// Double-buffered H -> ONE barrier per step.
// Launcher checks hipFuncGetAttributes(localSizeBytes) and falls back to the
// round-5 kernel if this one spilled to scratch (round-2 trap guard).
// ---------------------------------------------------------------------------
__global__ __launch_bounds__(512, 1) void rnn_scan_full(const float* __restrict__ XW,
                                                        const _Float16* __restrict__ Wrt,
                                                        const _Float16* __restrict__ Wrp,
                                                        float* __restrict__ Hout) {
    __shared__ __align__(16) _Float16 H[2][8192];   // 2 x 16 KiB

    const int tid  = threadIdx.x;
    const int wv   = tid >> 6;        // wave 0..7, owns cols [wv*64, wv*64+64)
    const int lane = tid & 63;
    const int fr   = lane & 15;
    const int fq   = lane >> 4;
    const int b0   = blockIdx.x * MB;

    // h0 = 0 (buffer 0 only)
    for (int i = tid; i < 4096; i += 512) ((unsigned int*)H[0])[i] = 0u;

    // ---- one-time preload: slices 0..2 (192 regs) ----
    f16x8 breg[3][16];
    #pragma unroll
    for (int s = 0; s < 3; ++s) {
        const int col = wv * 64 + s * 16 + fr;
        #pragma unroll
        for (int c = 0; c < 16; ++c)
            breg[s][c] = *(const f16x8*)&Wrt[(size_t)col * DH + c * 32 + fq * 8];
    }
    // ---- one-time preload: slice-3 chunks 0..14 (60 regs) ----
    f16x8 breg3[15];
    {
        const int col = wv * 64 + 48 + fr;
        #pragma unroll
        for (int c = 0; c < 15; ++c)
            breg3[c] = *(const f16x8*)&Wrt[(size_t)col * DH + c * 32 + fq * 8];
    }
    __syncthreads();

    const float* xbase = XW + (size_t)(b0 + fq * 4) * TSTEPS * DH + wv * 64 + fr;
    const f16x8* b15   = (const f16x8*)Wrp + wv * 1024 + 15 * 64 + lane;

    // epilogue write half-index (validated rounds 2/4/5):
    const int ebase = wv * 1024 + ((fr >> 3) * 16 + fq * 4) * 8 + (fr & 7);

    #pragma unroll 1
    for (int t = 0; t < TSTEPS; ++t) {
        const char* Hr = (const char*)H[t & 1];
        char*       Hw = (char*)H[(t + 1) & 1];

        // slice-3 chunk-15 stream: laundered so it stays a per-step L2 load
        int toff = 0;
        asm volatile("" : "+v"(toff));
        f16x8 bs = b15[toff];

        // xw for this step in C-frag layout (issued early, hidden under MFMA)
        float xv[4][4];
        #pragma unroll
        for (int s = 0; s < 4; ++s)
            #pragma unroll
            for (int r = 0; r < 4; ++r)
                xv[s][r] = xbase[(size_t)r * TSTEPS * DH + (size_t)t * DH + s * 16];

        f32x4 cc[4];
        #pragma unroll
        for (int s = 0; s < 4; ++s) cc[s] = (f32x4){0.f, 0.f, 0.f, 0.f};

        // 16 conflict-free b128 A-frag reads; ALL B operands register-resident
        #pragma unroll
        for (int c = 0; c < 15; ++c) {
            f16x8 af = *(const f16x8*)(Hr + c * 1024 + lane * 16);
            cc[0] = __builtin_amdgcn_mfma_f32_16x16x32_f16(af, breg[0][c], cc[0], 0, 0, 0);
            cc[1] = __builtin_amdgcn_mfma_f32_16x16x32_f16(af, breg[1][c], cc[1], 0, 0, 0);
            cc[2] = __builtin_amdgcn_mfma_f32_16x16x32_f16(af, breg[2][c], cc[2], 0, 0, 0);
            cc[3] = __builtin_amdgcn_mfma_f32_16x16x32_f16(af, breg3[c],   cc[3], 0, 0, 0);
        }
        {
            f16x8 af = *(const f16x8*)(Hr + 15 * 1024 + lane * 16);
            cc[0] = __builtin_amdgcn_mfma_f32_16x16x32_f16(af, breg[0][15], cc[0], 0, 0, 0);
            cc[1] = __builtin_amdgcn_mfma_f32_16x16x32_f16(af, breg[1][15], cc[1], 0, 0, 0);
            cc[2] = __builtin_amdgcn_mfma_f32_16x16x32_f16(af, breg[2][15], cc[2], 0, 0, 0);
            cc[3] = __builtin_amdgcn_mfma_f32_16x16x32_f16(af, bs,          cc[3], 0, 0, 0);
        }

        // epilogue: h = tanh(acc + xw) -> fragment-linear write into Hw
        #pragma unroll
        for (int s = 0; s < 4; ++s) {
            #pragma unroll
            for (int r = 0; r < 4; ++r) {
                const float a = cc[s][r] + xv[s][r];
                ((unsigned short*)Hw)[ebase + (s >> 1) * 512 + (s & 1) * 256 + r * 8] =
                    f2h_bits(ftanh(a));
            }
        }
        __syncthreads();   // Hw complete before next step reads it
    }

    // final output: H_T lives in H[0] (TSTEPS even). Coalesced float4 stores.
    {
        const int m  = tid >> 5;           // 0..15
        const int cg = tid & 31;           // 16-col group
        const int cb = cg * 16;
        const int c  = cg >> 1;            // chunk
        const int fb = (cg & 1) * 2;       // fq' base
        const char* Hb0 = (const char*)H[0];
        #pragma unroll
        for (int g = 0; g < 2; ++g) {
            f16x8 v = *(const f16x8*)(Hb0 + c * 1024 + ((fb + g) * 16 + m) * 16);
            float4 o0 = { (float)v[0], (float)v[1], (float)v[2], (float)v[3] };
            float4 o1 = { (float)v[4], (float)v[5], (float)v[6], (float)v[7] };
            *(float4*)&Hout[(size_t)(b0 + m) * DH + cb + g * 8]     = o0;
            *(float4*)&Hout[(size_t)(b0 + m) * DH + cb + g * 8 + 4] = o1;
        }
    }
}

// ---------------------------------------------------------------------------
// K2b (fallback, round-5 proven 1717 us): slice-3 B from LDS (chunks 0..14)
// + chunk-15 L2 stream. Identical numerics.
// ---------------------------------------------------------------------------
__global__ __launch_bounds__(512, 1) void rnn_scan_lds(const float* __restrict__ XW,
                                                       const _Float16* __restrict__ Wrt,
                                                       const _Float16* __restrict__ Wrp,
                                                       float* __restrict__ Hout) {
    extern __shared__ __align__(16) char lds[];
    char* bwl   = lds;                 // [8 waves][15 chunks][1024 B]
    char* Hbase = lds + BLDS_ALL;      // 2 x 16384 B, fragment-linear

    const int tid  = threadIdx.x;
    const int wv   = tid >> 6;
    const int lane = tid & 63;
    const int fr   = lane & 15;
    const int fq   = lane >> 4;
    const int b0   = blockIdx.x * MB;

    for (int i = tid; i < 4096; i += 512) ((unsigned int*)Hbase)[i] = 0u;

    f16x8 breg[3][16];
    #pragma unroll
    for (int s = 0; s < 3; ++s) {
        const int col = wv * 64 + s * 16 + fr;
        #pragma unroll
        for (int c = 0; c < 16; ++c)
            breg[s][c] = *(const f16x8*)&Wrt[(size_t)col * DH + c * 32 + fq * 8];
    }
    {
        const f16x8* src = (const f16x8*)Wrp + wv * 1024 + lane;
        char* dst = bwl + wv * BLDS_W + lane * 16;
        #pragma unroll
        for (int c = 0; c < 15; ++c)
            *(f16x8*)(dst + c * 1024) = src[c * 64];
    }
    __syncthreads();

    const float* xbase = XW + (size_t)(b0 + fq * 4) * TSTEPS * DH + wv * 64 + fr;
    const f16x8* b15   = (const f16x8*)Wrp + wv * 1024 + 15 * 64 + lane;
    const char*  bw    = bwl + wv * BLDS_W + lane * 16;

    const int ebase = wv * 1024 + ((fr >> 3) * 16 + fq * 4) * 8 + (fr & 7);

    #pragma unroll 1
    for (int t = 0; t < TSTEPS; ++t) {
        const char* Hr = Hbase + ((t & 1) << 14);
        char*       Hw = Hbase + (((t + 1) & 1) << 14);

        int toff = 0;
        asm volatile("" : "+v"(toff));
        f16x8 bs = b15[toff];

        float xv[4][4];
        #pragma unroll
        for (int s = 0; s < 4; ++s)
            #pragma unroll
            for (int r = 0; r < 4; ++r)
                xv[s][r] = xbase[(size_t)r * TSTEPS * DH + (size_t)t * DH + s * 16];

        f32x4 cc[4];
        #pragma unroll
        for (int s = 0; s < 4; ++s) cc[s] = (f32x4){0.f, 0.f, 0.f, 0.f};

        #pragma unroll
        for (int c = 0; c < 15; ++c) {
            f16x8 af = *(const f16x8*)(Hr + c * 1024 + lane * 16);
            f16x8 bf = *(const f16x8*)(bw + c * 1024);
            cc[0] = __builtin_amdgcn_mfma_f32_16x16x32_f16(af, breg[0][c], cc[0], 0, 0, 0);
            cc[1] = __builtin_amdgcn_mfma_f32_16x16x32_f16(af, breg[1][c], cc[1], 0, 0, 0);
            cc[2] = __builtin_amdgcn_mfma_f32_16x16x32_f16(af, breg[2][c], cc[2], 0, 0, 0);
            cc[3] = __builtin_amdgcn_mfma_f32_16x16x32_f16(af, bf,         cc[3], 0, 0, 0);
        }
        {
            f16x8 af = *(const f16x8*)(Hr + 15 * 1024 + lane * 16);
            cc[0] = __builtin_amdgcn_mfma_f32_16x16x32_f16(af, breg[0][15], cc[0], 0, 0, 0);
            cc[1] = __builtin_amdgcn_mfma_f32_16x16x32_f16(af, breg[1][15], cc[1], 0, 0, 0);
            cc[2] = __builtin_amdgcn_mfma_f32_16x16x32_f16(af, breg[2][15], cc[2], 0, 0, 0);
            cc[3] = __builtin_amdgcn_mfma_f32_16x16x32_f16(af, bs,          cc[3], 0, 0, 0);
        }

        #pragma unroll
        for (int s = 0; s < 4; ++s) {
            #pragma unroll
            for (int r = 0; r < 4; ++r) {
                const float a = cc[s][r] + xv[s][r];
                ((unsigned short*)Hw)[ebase + (s >> 1) * 512 + (s & 1) * 256 + r * 8] =
                    f2h_bits(ftanh(a));
            }
        }
        __syncthreads();
    }

    {
        const int m  = tid >> 5;
        const int cg = tid & 31;
        const int cb = cg * 16;
        const int c  = cg >> 1;
        const int fb = (cg & 1) * 2;
        const char* Hb0 = Hbase;
        #pragma unroll
        for (int g = 0; g < 2; ++g) {
            f16x8 v = *(const f16x8*)(Hb0 + c * 1024 + ((fb + g) * 16 + m) * 16);
            float4 o0 = { (float)v[0], (float)v[1], (float)v[2], (float)v[3] };
            float4 o1 = { (float)v[4], (float)v[5], (float)v[6], (float)v[7] };
            *(float4*)&Hout[(size_t)(b0 + m) * DH + cb + g * 8]     = o0;
            *(float4*)&Hout[(size_t)(b0 + m) * DH + cb + g * 8 + 4] = o1;
        }
    }
}

// ---------------------------------------------------------------------------
// launch
// ---------------------------------------------------------------------------
extern "C" void kernel_launch(void* const* d_in, const int* in_sizes, int n_in,
                              void* d_out, int out_size, void* d_ws, size_t ws_size,
                              hipStream_t stream) {
    const float* x  = (const float*)d_in[0];
    const float* W  = (const float*)d_in[1];
    const float* Wr = (const float*)d_in[2];
    const float* bv = (const float*)d_in[3];
    float* out = (float*)d_out;

    const size_t XW_BYTES  = (size_t)MDIM * DH * sizeof(float);     // 128 MiB
    const size_t WRT_BYTES = (size_t)DH * DH * sizeof(_Float16);    // 512 KiB
    const size_t WRP_BYTES = (size_t)8 * 16 * 64 * 8 * sizeof(_Float16); // 128 KiB
    const size_t XH_BYTES  = (size_t)MDIM * DIN * sizeof(_Float16); // 64 MiB
    const size_t WT_BYTES  = (size_t)DIN * DH * sizeof(_Float16);   // 512 KiB

    const size_t SCAN_MIN = XW_BYTES + WRT_BYTES + WRP_BYTES;
    if (ws_size < SCAN_MIN) return;

    char* base = (char*)d_ws;
    float*    xw  = (float*)base;
    _Float16* wrt = (_Float16*)(base + XW_BYTES);
    _Float16* wrp = (_Float16*)(base + XW_BYTES + WRT_BYTES);

    // Static host-side decision: use the full-residency scan only if it
    // compiled without scratch spill (round-2 trap guard). Pure module
    // query -- no stream interaction, graph-capture safe.
    static int use_full = -1;
    if (use_full < 0) {
        hipFuncAttributes fa;
        if (hipFuncGetAttributes(&fa, (const void*)rnn_scan_full) == hipSuccess &&
            fa.localSizeBytes == 0)
            use_full = 1;
        else
            use_full = 0;
    }

    hipFuncSetAttribute((const void*)rnn_scan_lds,
                        hipFuncAttributeMaxDynamicSharedMemorySize, K2_LDS);

    transpose_w<<<dim3(64), dim3(256), 0, stream>>>(Wr, wrt);
    pack_b3<<<dim3(16), dim3(512), 0, stream>>>(wrt, wrp);

    if (ws_size >= SCAN_MIN + XH_BYTES + WT_BYTES) {
        _Float16* xh = (_Float16*)(base + SCAN_MIN);
        _Float16* wt = (_Float16*)(base + SCAN_MIN + XH_BYTES);
        convert_x<<<dim3(2048), dim3(256), 0, stream>>>(x, xh, MDIM * DIN / 8);
        transpose_w<<<dim3(64), dim3(256), 0, stream>>>(W, wt);
        gemm_xw_mfma<<<dim3((MDIM / 128) * (DH / 128)), dim3(256), 0, stream>>>(
            xh, wt, bv, xw);
    } else {
        gemm_xw<<<dim3((MDIM / 64) * (DH / 64)), dim3(256), 0, stream>>>(x, W, bv, xw);
    }

    if (use_full)
        rnn_scan_full<<<dim3(BATCH / MB), dim3(512), 0, stream>>>(xw, wrt, wrp, out);
    else
        rnn_scan_lds<<<dim3(BATCH / MB), dim3(512), K2_LDS, stream>>>(xw, wrt, wrp, out);
}

// Round 7
// 1975.077 us; speedup vs baseline: 1.0040x; 1.0040x over previous
//
#include <hip/hip_runtime.h>
#include <math.h>

// Problem constants (B, T, D_IN, D_OUT) = (64, 1024, 512, 512)
#define BATCH   64
#define TSTEPS  1024
#define DIN     512
#define DH      512
#define MDIM    (BATCH * TSTEPS)
#define MB      16

// Fallback (round-5) K2 LDS layout: [8 waves][15 chunks][1024 B] B + 2 x 16 KiB H
#define BLDS_W   15360
#define BLDS_ALL 122880
#define K2_LDS   (BLDS_ALL + 2 * 16384)   // 155648 <= 163840

typedef _Float16 f16x8 __attribute__((ext_vector_type(8)));
typedef float    f32x4 __attribute__((ext_vector_type(4)));

__device__ inline unsigned short f2h_bits(float x) {
    _Float16 h = (_Float16)x;
    return __builtin_bit_cast(unsigned short, h);
}
// fast tanh: 1 - 2/(exp2(2x*log2e)+1); saturates correctly incl. inf
__device__ inline float ftanh(float x) {
    float e = __builtin_amdgcn_exp2f(x * 2.88539008177792681472f);
    return 1.0f - 2.0f * __builtin_amdgcn_rcpf(e + 1.0f);
}

// ---------------------------------------------------------------------------
// K1a: convert x (fp32) -> Xh (fp16)
// ---------------------------------------------------------------------------
__global__ __launch_bounds__(256) void convert_x(const float* __restrict__ x,
                                                 _Float16* __restrict__ xh,
                                                 int nvec) {
    int i = blockIdx.x * blockDim.x + threadIdx.x;
    int stride = gridDim.x * blockDim.x;
    for (; i < nvec; i += stride) {
        const float4* p = (const float4*)x + 2 * (size_t)i;
        float4 a = p[0], b = p[1];
        f16x8 o = { (_Float16)a.x, (_Float16)a.y, (_Float16)a.z, (_Float16)a.w,
                    (_Float16)b.x, (_Float16)b.y, (_Float16)b.z, (_Float16)b.w };
        ((f16x8*)xh)[i] = o;
    }
}

// ---------------------------------------------------------------------------
// K1b: Wt[n][k] = (fp16) W[k][n]   (also reused for Wr)
// ---------------------------------------------------------------------------
__global__ __launch_bounds__(256) void transpose_w(const float* __restrict__ W,
                                                   _Float16* __restrict__ Wt) {
    __shared__ float tile[64][65];
    const int t  = threadIdx.x;
    const int c  = t & 63;
    const int r0 = t >> 6;
    const int bn = blockIdx.x & 7;
    const int bk = blockIdx.x >> 3;
    const int k0 = bk * 64, n0 = bn * 64;
    #pragma unroll
    for (int i = 0; i < 16; ++i)
        tile[r0 + 4 * i][c] = W[(size_t)(k0 + r0 + 4 * i) * DH + n0 + c];
    __syncthreads();
    #pragma unroll
    for (int i = 0; i < 16; ++i)
        Wt[(size_t)(n0 + r0 + 4 * i) * DIN + k0 + c] = (_Float16)tile[c][r0 + 4 * i];
}

// ---------------------------------------------------------------------------
// K1d: pack slice-3 B-fragments (cols wv*64+48 .. +63) fragment-contiguous:
//   Wrp[wv*1024 + c*64 + lane] = frag (f16x8). (fallback kernel only)
// ---------------------------------------------------------------------------
__global__ __launch_bounds__(512) void pack_b3(const _Float16* __restrict__ Wrt,
                                               _Float16* __restrict__ Wrp) {
    const int i  = blockIdx.x * 512 + threadIdx.x;   // 0..8191
    const int wv = i >> 10;
    const int c  = (i >> 6) & 15;
    const int l  = i & 63;
    const int col = wv * 64 + 48 + (l & 15);
    const int k0  = c * 32 + (l >> 4) * 8;
    ((f16x8*)Wrp)[i] = *(const f16x8*)&Wrt[(size_t)col * DIN + k0];
}

// ---------------------------------------------------------------------------
// K1c: XW = Xh @ Wt^T + bias via mfma_f32_16x16x32_f16 (validated earlier)
// ---------------------------------------------------------------------------
__global__ __launch_bounds__(256) void gemm_xw_mfma(const _Float16* __restrict__ Xh,
                                                    const _Float16* __restrict__ Wt,
                                                    const float* __restrict__ bias,
                                                    float* __restrict__ XW) {
    __shared__ __align__(16) _Float16 Ah[128][32];
    __shared__ __align__(16) _Float16 Bh[128][32];

    const int tid  = threadIdx.x;
    const int wv   = tid >> 6;
    const int lane = tid & 63;
    const int bn   = blockIdx.x & 3;
    const int bm   = blockIdx.x >> 2;
    const int m0   = bm * 128;
    const int n0   = bn * 128;

    const int mbase = (wv >> 1) * 64;
    const int nbase = (wv & 1) * 64;
    const int fr    = lane & 15;
    const int fq    = lane >> 4;

    f32x4 acc[4][4];
    #pragma unroll
    for (int i = 0; i < 4; ++i)
        #pragma unroll
        for (int j = 0; j < 4; ++j)
            acc[i][j] = (f32x4){0.f, 0.f, 0.f, 0.f};

    for (int kc = 0; kc < DIN / 32; ++kc) {
        const int k0 = kc * 32;
#if __has_builtin(__builtin_amdgcn_global_load_lds)
        #pragma unroll
        for (int q = 0; q < 2; ++q) {
            const int rb = wv * 2 + q;
            const int gr = (rb * 16) + (lane >> 2);
            const int gc = (lane & 3) * 8;
            const _Float16* ga = Xh + (size_t)(m0 + gr) * DIN + k0 + gc;
            const _Float16* gb = Wt + (size_t)(n0 + gr) * DIN + k0 + gc;
            __builtin_amdgcn_global_load_lds(
                (const __attribute__((address_space(1))) void*)ga,
                (__attribute__((address_space(3))) void*)&Ah[rb * 16][0], 16, 0, 0);
            __builtin_amdgcn_global_load_lds(
                (const __attribute__((address_space(1))) void*)gb,
                (__attribute__((address_space(3))) void*)&Bh[rb * 16][0], 16, 0, 0);
        }
#else
        #pragma unroll
        for (int q = 0; q < 2; ++q) {
            const int h0 = (q * 256 + tid) * 8;
            const int row = h0 >> 5, col = h0 & 31;
            *((uint4*)Ah + (q * 256 + tid)) =
                *(const uint4*)(Xh + (size_t)(m0 + row) * DIN + k0 + col);
            *((uint4*)Bh + (q * 256 + tid)) =
                *(const uint4*)(Wt + (size_t)(n0 + row) * DIN + k0 + col);
        }
#endif
        __syncthreads();

        f16x8 af[4], bf[4];
        #pragma unroll
        for (int mt = 0; mt < 4; ++mt)
            af[mt] = *(const f16x8*)&Ah[mbase + mt * 16 + fr][fq * 8];
        #pragma unroll
        for (int nt = 0; nt < 4; ++nt)
            bf[nt] = *(const f16x8*)&Bh[nbase + nt * 16 + fr][fq * 8];
        #pragma unroll
        for (int mt = 0; mt < 4; ++mt)
            #pragma unroll
            for (int nt = 0; nt < 4; ++nt)
                acc[mt][nt] = __builtin_amdgcn_mfma_f32_16x16x32_f16(
                    af[mt], bf[nt], acc[mt][nt], 0, 0, 0);
        __syncthreads();
    }

    #pragma unroll
    for (int nt = 0; nt < 4; ++nt) {
        const int col = n0 + nbase + nt * 16 + fr;
        const float bvl = bias[col];
        #pragma unroll
        for (int mt = 0; mt < 4; ++mt) {
            #pragma unroll
            for (int r = 0; r < 4; ++r) {
                const int row = m0 + mbase + mt * 16 + fq * 4 + r;
                XW[(size_t)row * DH + col] = acc[mt][nt][r] + bvl;
            }
        }
    }
}

// ---------------------------------------------------------------------------
// K1 fallback (fp32 VALU GEMM)
// ---------------------------------------------------------------------------
__global__ __launch_bounds__(256) void gemm_xw(const float* __restrict__ X,
                                               const float* __restrict__ W,
                                               const float* __restrict__ bias,
                                               float* __restrict__ XW) {
    __shared__ float As[16][68];
    __shared__ float Bs[16][68];
    const int tid = threadIdx.x;
    const int bx  = blockIdx.x & 7;
    const int by  = blockIdx.x >> 3;
    const int m0  = by * 64, n0 = bx * 64;
    const int ty = tid >> 4, tx = tid & 15;
    const int arow = tid >> 2, akq = (tid & 3) * 4;
    const int brow = tid >> 4, bcq = (tid & 15) * 4;
    float acc[4][4] = {{0.f}};
    for (int k0 = 0; k0 < DIN; k0 += 16) {
        float4 av = *(const float4*)&X[(size_t)(m0 + arow) * DIN + k0 + akq];
        float4 bv = *(const float4*)&W[(size_t)(k0 + brow) * DH + n0 + bcq];
        __syncthreads();
        As[akq + 0][arow] = av.x; As[akq + 1][arow] = av.y;
        As[akq + 2][arow] = av.z; As[akq + 3][arow] = av.w;
        *(float4*)&Bs[brow][bcq] = bv;
        __syncthreads();
        #pragma unroll
        for (int k = 0; k < 16; ++k) {
            float4 a = *(const float4*)&As[k][ty * 4];
            float4 b = *(const float4*)&Bs[k][tx * 4];
            float ar[4] = {a.x, a.y, a.z, a.w};
            float br[4] = {b.x, b.y, b.z, b.w};
            #pragma unroll
            for (int i = 0; i < 4; ++i)
                #pragma unroll
                for (int j = 0; j < 4; ++j)
                    acc[i][j] = fmaf(ar[i], br[j], acc[i][j]);
        }
    }
    float4 bv = *(const float4*)&bias[n0 + tx * 4];
    const float br[4] = {bv.x, bv.y, bv.z, bv.w};
    #pragma unroll
    for (int i = 0; i < 4; ++i) {
        float4 o;
        o.x = acc[i][0] + br[0]; o.y = acc[i][1] + br[1];
        o.z = acc[i][2] + br[2]; o.w = acc[i][3] + br[3];
        *(float4*)&XW[(size_t)(m0 + ty * 4 + i) * DH + n0 + tx * 4] = o;
    }
}

// ---------------------------------------------------------------------------
// K2a (preferred): WIDE scan -- 4 wgs x 1024 thr (16 waves, 4 waves/SIMD).
// Wave wv owns cols [wv*32, wv*32+32) = 2 slices: breg[2][16] = 128 regs,
// FULLY resident (reg budget at 4 waves/SIMD = 512/wave; ~200 needed).
//   => ZERO per-step B LDS traffic AND 2x the waves to hide the trans-pipe
//      (tanh: 16 cyc/instr quarter-rate) + MFMA + HBM-xv latency that
//      dominated the 8-wave kernels (round-6 analysis: LDS BW was only
//      ~25% of the measured step; occupancy was the limiter).
// H fp16, fragment-linear (validated r2/r4/r5): conflict-free b128 A-reads.
// Double-buffered H -> ONE barrier per step. Static LDS 32 KiB.
// Launcher falls back to the round-5 kernel if this one spilled (guard
// proven effective in round 6).
// ---------------------------------------------------------------------------
__global__ __launch_bounds__(1024, 1) void rnn_scan_wide(const float* __restrict__ XW,
                                                         const _Float16* __restrict__ Wrt,
                                                         float* __restrict__ Hout) {
    __shared__ __align__(16) _Float16 H[2][8192];   // 2 x 16 KiB

    const int tid  = threadIdx.x;
    const int wv   = tid >> 6;        // wave 0..15, owns cols [wv*32, wv*32+32)
    const int lane = tid & 63;
    const int fr   = lane & 15;
    const int fq   = lane >> 4;
    const int b0   = blockIdx.x * MB;

    // h0 = 0 (buffer 0 only)
    for (int i = tid; i < 4096; i += 1024) ((unsigned int*)H[0])[i] = 0u;

    // ---- one-time preload: both col-slices -> registers (128 regs) ----
    f16x8 breg[2][16];
    #pragma unroll
    for (int s = 0; s < 2; ++s) {
        const int col = wv * 32 + s * 16 + fr;
        #pragma unroll
        for (int c = 0; c < 16; ++c)
            breg[s][c] = *(const f16x8*)&Wrt[(size_t)col * DH + c * 32 + fq * 8];
    }
    __syncthreads();

    const float* xbase = XW + (size_t)(b0 + fq * 4) * TSTEPS * DH + wv * 32 + fr;

    // epilogue write half-index (same validated mapping, 32-col wave):
    //   col = wv*32 + s*16 + fr -> chunk = wv, koff = s*16 + fr
    //   idx = wv*512 + ((koff>>3)*16 + fq*4 + r)*8 + (fr&7)
    //       = ebase + s*256 + r*8
    const int ebase = wv * 512 + ((fr >> 3) * 16 + fq * 4) * 8 + (fr & 7);

    #pragma unroll 1
    for (int t = 0; t < TSTEPS; ++t) {
        const char* Hr = (const char*)H[t & 1];
        char*       Hw = (char*)H[(t + 1) & 1];

        // xw for this step in C-frag layout (issued early, hidden under MFMA)
        float xv[2][4];
        #pragma unroll
        for (int s = 0; s < 2; ++s)
            #pragma unroll
            for (int r = 0; r < 4; ++r)
                xv[s][r] = xbase[(size_t)r * TSTEPS * DH + (size_t)t * DH + s * 16];

        f32x4 cc[2];
        cc[0] = (f32x4){0.f, 0.f, 0.f, 0.f};
        cc[1] = (f32x4){0.f, 0.f, 0.f, 0.f};

        // 16 conflict-free b128 A-frag reads; ALL B operands register-resident
        #pragma unroll
        for (int c = 0; c < 16; ++c) {
            f16x8 af = *(const f16x8*)(Hr + c * 1024 + lane * 16);
            cc[0] = __builtin_amdgcn_mfma_f32_16x16x32_f16(af, breg[0][c], cc[0], 0, 0, 0);
            cc[1] = __builtin_amdgcn_mfma_f32_16x16x32_f16(af, breg[1][c], cc[1], 0, 0, 0);
        }

        // epilogue: h = tanh(acc + xw) -> fragment-linear write into Hw
        #pragma unroll
        for (int s = 0; s < 2; ++s) {
            #pragma unroll
            for (int r = 0; r < 4; ++r) {
                const float a = cc[s][r] + xv[s][r];
                ((unsigned short*)Hw)[ebase + s * 256 + r * 8] = f2h_bits(ftanh(a));
            }
        }
        __syncthreads();   // Hw complete before next step reads it
    }

    // final output: H_T in H[0] (TSTEPS even). 1024 thr x 8 cols, coalesced.
    {
        const int m   = tid >> 6;          // 0..15
        const int cg  = tid & 63;          // 8-col group
        const int c   = cg >> 2;           // chunk
        const int fqp = cg & 3;
        const char* Hb0 = (const char*)H[0];
        f16x8 v = *(const f16x8*)(Hb0 + c * 1024 + (fqp * 16 + m) * 16);
        float4 o0 = { (float)v[0], (float)v[1], (float)v[2], (float)v[3] };
        float4 o1 = { (float)v[4], (float)v[5], (float)v[6], (float)v[7] };
        *(float4*)&Hout[(size_t)(b0 + m) * DH + cg * 8]     = o0;
        *(float4*)&Hout[(size_t)(b0 + m) * DH + cg * 8 + 4] = o1;
    }
}

// ---------------------------------------------------------------------------
// K2b (fallback, round-5 proven 1717 us): 8 waves; slice-3 B from LDS
// (chunks 0..14) + chunk-15 L2 stream. Identical numerics.
// ---------------------------------------------------------------------------
__global__ __launch_bounds__(512, 1) void rnn_scan_lds(const float* __restrict__ XW,
                                                       const _Float16* __restrict__ Wrt,
                                                       const _Float16* __restrict__ Wrp,
                                                       float* __restrict__ Hout) {
    extern __shared__ __align__(16) char lds[];
    char* bwl   = lds;                 // [8 waves][15 chunks][1024 B]
    char* Hbase = lds + BLDS_ALL;      // 2 x 16384 B, fragment-linear

    const int tid  = threadIdx.x;
    const int wv   = tid >> 6;
    const int lane = tid & 63;
    const int fr   = lane & 15;
    const int fq   = lane >> 4;
    const int b0   = blockIdx.x * MB;

    for (int i = tid; i < 4096; i += 512) ((unsigned int*)Hbase)[i] = 0u;

    f16x8 breg[3][16];
    #pragma unroll
    for (int s = 0; s < 3; ++s) {
        const int col = wv * 64 + s * 16 + fr;
        #pragma unroll
        for (int c = 0; c < 16; ++c)
            breg[s][c] = *(const f16x8*)&Wrt[(size_t)col * DH + c * 32 + fq * 8];
    }
    {
        const f16x8* src = (const f16x8*)Wrp + wv * 1024 + lane;
        char* dst = bwl + wv * BLDS_W + lane * 16;
        #pragma unroll
        for (int c = 0; c < 15; ++c)
            *(f16x8*)(dst + c * 1024) = src[c * 64];
    }
    __syncthreads();

    const float* xbase = XW + (size_t)(b0 + fq * 4) * TSTEPS * DH + wv * 64 + fr;
    const f16x8* b15   = (const f16x8*)Wrp + wv * 1024 + 15 * 64 + lane;
    const char*  bw    = bwl + wv * BLDS_W + lane * 16;

    const int ebase = wv * 1024 + ((fr >> 3) * 16 + fq * 4) * 8 + (fr & 7);

    #pragma unroll 1
    for (int t = 0; t < TSTEPS; ++t) {
        const char* Hr = Hbase + ((t & 1) << 14);
        char*       Hw = Hbase + (((t + 1) & 1) << 14);

        int toff = 0;
        asm volatile("" : "+v"(toff));
        f16x8 bs = b15[toff];

        float xv[4][4];
        #pragma unroll
        for (int s = 0; s < 4; ++s)
            #pragma unroll
            for (int r = 0; r < 4; ++r)
                xv[s][r] = xbase[(size_t)r * TSTEPS * DH + (size_t)t * DH + s * 16];

        f32x4 cc[4];
        #pragma unroll
        for (int s = 0; s < 4; ++s) cc[s] = (f32x4){0.f, 0.f, 0.f, 0.f};

        #pragma unroll
        for (int c = 0; c < 15; ++c) {
            f16x8 af = *(const f16x8*)(Hr + c * 1024 + lane * 16);
            f16x8 bf = *(const f16x8*)(bw + c * 1024);
            cc[0] = __builtin_amdgcn_mfma_f32_16x16x32_f16(af, breg[0][c], cc[0], 0, 0, 0);
            cc[1] = __builtin_amdgcn_mfma_f32_16x16x32_f16(af, breg[1][c], cc[1], 0, 0, 0);
            cc[2] = __builtin_amdgcn_mfma_f32_16x16x32_f16(af, breg[2][c], cc[2], 0, 0, 0);
            cc[3] = __builtin_amdgcn_mfma_f32_16x16x32_f16(af, bf,         cc[3], 0, 0, 0);
        }
        {
            f16x8 af = *(const f16x8*)(Hr + 15 * 1024 + lane * 16);
            cc[0] = __builtin_amdgcn_mfma_f32_16x16x32_f16(af, breg[0][15], cc[0], 0, 0, 0);
            cc[1] = __builtin_amdgcn_mfma_f32_16x16x32_f16(af, breg[1][15], cc[1], 0, 0, 0);
            cc[2] = __builtin_amdgcn_mfma_f32_16x16x32_f16(af, breg[2][15], cc[2], 0, 0, 0);
            cc[3] = __builtin_amdgcn_mfma_f32_16x16x32_f16(af, bs,          cc[3], 0, 0, 0);
        }

        #pragma unroll
        for (int s = 0; s < 4; ++s) {
            #pragma unroll
            for (int r = 0; r < 4; ++r) {
                const float a = cc[s][r] + xv[s][r];
                ((unsigned short*)Hw)[ebase + (s >> 1) * 512 + (s & 1) * 256 + r * 8] =
                    f2h_bits(ftanh(a));
            }
        }
        __syncthreads();
    }

    {
        const int m  = tid >> 5;
        const int cg = tid & 31;
        const int cb = cg * 16;
        const int c  = cg >> 1;
        const int fb = (cg & 1) * 2;
        const char* Hb0 = Hbase;
        #pragma unroll
        for (int g = 0; g < 2; ++g) {
            f16x8 v = *(const f16x8*)(Hb0 + c * 1024 + ((fb + g) * 16 + m) * 16);
            float4 o0 = { (float)v[0], (float)v[1], (float)v[2], (float)v[3] };
            float4 o1 = { (float)v[4], (float)v[5], (float)v[6], (float)v[7] };
            *(float4*)&Hout[(size_t)(b0 + m) * DH + cb + g * 8]     = o0;
            *(float4*)&Hout[(size_t)(b0 + m) * DH + cb + g * 8 + 4] = o1;
        }
    }
}

// ---------------------------------------------------------------------------
// launch
// ---------------------------------------------------------------------------
extern "C" void kernel_launch(void* const* d_in, const int* in_sizes, int n_in,
                              void* d_out, int out_size, void* d_ws, size_t ws_size,
                              hipStream_t stream) {
    const float* x  = (const float*)d_in[0];
    const float* W  = (const float*)d_in[1];
    const float* Wr = (const float*)d_in[2];
    const float* bv = (const float*)d_in[3];
    float* out = (float*)d_out;

    const size_t XW_BYTES  = (size_t)MDIM * DH * sizeof(float);     // 128 MiB
    const size_t WRT_BYTES = (size_t)DH * DH * sizeof(_Float16);    // 512 KiB
    const size_t WRP_BYTES = (size_t)8 * 16 * 64 * 8 * sizeof(_Float16); // 128 KiB
    const size_t XH_BYTES  = (size_t)MDIM * DIN * sizeof(_Float16); // 64 MiB
    const size_t WT_BYTES  = (size_t)DIN * DH * sizeof(_Float16);   // 512 KiB

    const size_t SCAN_MIN = XW_BYTES + WRT_BYTES + WRP_BYTES;
    if (ws_size < SCAN_MIN) return;

    char* base = (char*)d_ws;
    float*    xw  = (float*)base;
    _Float16* wrt = (_Float16*)(base + XW_BYTES);
    _Float16* wrp = (_Float16*)(base + XW_BYTES + WRT_BYTES);

    // Host-side guard (proven in round 6): use the wide scan only if it
    // compiled without scratch spill. Pure module query, graph-capture safe.
    static int use_wide = -1;
    if (use_wide < 0) {
        hipFuncAttributes fa;
        if (hipFuncGetAttributes(&fa, (const void*)rnn_scan_wide) == hipSuccess &&
            fa.localSizeBytes == 0)
            use_wide = 1;
        else
            use_wide = 0;
    }

    hipFuncSetAttribute((const void*)rnn_scan_lds,
                        hipFuncAttributeMaxDynamicSharedMemorySize, K2_LDS);

    transpose_w<<<dim3(64), dim3(256), 0, stream>>>(Wr, wrt);
    pack_b3<<<dim3(16), dim3(512), 0, stream>>>(wrt, wrp);

    if (ws_size >= SCAN_MIN + XH_BYTES + WT_BYTES) {
        _Float16* xh = (_Float16*)(base + SCAN_MIN);
        _Float16* wt = (_Float16*)(base + SCAN_MIN + XH_BYTES);
        convert_x<<<dim3(2048), dim3(256), 0, stream>>>(x, xh, MDIM * DIN / 8);
        transpose_w<<<dim3(64), dim3(256), 0, stream>>>(W, wt);
        gemm_xw_mfma<<<dim3((MDIM / 128) * (DH / 128)), dim3(256), 0, stream>>>(
            xh, wt, bv, xw);
    } else {
        gemm_xw<<<dim3((MDIM / 64) * (DH / 64)), dim3(256), 0, stream>>>(x, W, bv, xw);
    }

    if (use_wide)
        rnn_scan_wide<<<dim3(BATCH / MB), dim3(1024), 0, stream>>>(xw, wrt, out);
    else
        rnn_scan_lds<<<dim3(BATCH / MB), dim3(512), K2_LDS, stream>>>(xw, wrt, wrp, out);
}